// Round 1
// baseline (701.916 us; speedup 1.0000x reference)
//
#include <hip/hip_runtime.h>

// GCN: N=100000 nodes (4 feats), E=3.2M edges, G=1024 graphs.
// out = mean-pool(tanh(gcn2(tanh(gcn1(embed(x)))))) @ W3.T + b3
//
// gcn_conv rewritten: u[i] = (h[i] @ W^T) * dinv[i];
// out[c] = dinv[c] * (sum_{edges r->c} u[r] + u[c]) + b   (self-loop folded in)

constexpr int BLK = 256;

__global__ void k_init(float* __restrict__ deg, float* __restrict__ pooled,
                       float* __restrict__ cnt, int n, int g) {
    int i = blockIdx.x * BLK + threadIdx.x;
    if (i < n) deg[i] = 1.0f;          // self-loop contribution to degree
    if (i < g * 8) pooled[i] = 0.0f;
    if (i < g) cnt[i] = 0.0f;
}

__global__ void k_deg(const int* __restrict__ col, float* __restrict__ deg, int E) {
    int e = blockIdx.x * BLK + threadIdx.x;
    if (e < E) atomicAdd(&deg[col[e]], 1.0f);
}

// h0 = [x0*Wemb + bemb (4), x1, x2, x3]; u1 = (h0 @ W1^T) * dinv; acc1 seeded with u1
__global__ void k_node1(const float* __restrict__ x, float* __restrict__ deg_dinv,
                        const float* __restrict__ Wemb, const float* __restrict__ bemb,
                        const float* __restrict__ W1,
                        float* __restrict__ u1, float* __restrict__ acc1, int n) {
    int i = blockIdx.x * BLK + threadIdx.x;
    if (i >= n) return;
    float4 xi = ((const float4*)x)[i];
    float h0[7];
#pragma unroll
    for (int j = 0; j < 4; j++) h0[j] = xi.x * Wemb[j] + bemb[j];
    h0[4] = xi.y; h0[5] = xi.z; h0[6] = xi.w;
    float d = rsqrtf(deg_dinv[i]);
    deg_dinv[i] = d;  // reuse buffer as dinv
#pragma unroll
    for (int f = 0; f < 16; f++) {
        float s = 0.0f;
#pragma unroll
        for (int j = 0; j < 7; j++) s += h0[j] * W1[f * 7 + j];
        s *= d;
        u1[i * 16 + f] = s;
        acc1[i * 16 + f] = s;   // self-loop seed
    }
}

__global__ void k_scatter16(const int* __restrict__ row, const int* __restrict__ col,
                            const float* __restrict__ u, float* __restrict__ acc, int total) {
    int tid = blockIdx.x * BLK + threadIdx.x;
    if (tid >= total) return;
    int e = tid >> 4, f = tid & 15;
    int r = row[e], c = col[e];
    atomicAdd(&acc[c * 16 + f], u[r * 16 + f]);
}

__global__ void k_node2(const float* __restrict__ dinv, const float* __restrict__ acc1,
                        const float* __restrict__ b1, const float* __restrict__ W2,
                        float* __restrict__ u2, float* __restrict__ acc2, int n) {
    int i = blockIdx.x * BLK + threadIdx.x;
    if (i >= n) return;
    float d = dinv[i];
    float h1[16];
#pragma unroll
    for (int f = 0; f < 16; f++) h1[f] = tanhf(d * acc1[i * 16 + f] + b1[f]);
#pragma unroll
    for (int g = 0; g < 8; g++) {
        float s = 0.0f;
#pragma unroll
        for (int f = 0; f < 16; f++) s += h1[f] * W2[g * 16 + f];
        s *= d;
        u2[i * 8 + g] = s;
        acc2[i * 8 + g] = s;   // self-loop seed
    }
}

__global__ void k_scatter8(const int* __restrict__ row, const int* __restrict__ col,
                           const float* __restrict__ u, float* __restrict__ acc, int total) {
    int tid = blockIdx.x * BLK + threadIdx.x;
    if (tid >= total) return;
    int e = tid >> 3, f = tid & 7;
    int r = row[e], c = col[e];
    atomicAdd(&acc[c * 8 + f], u[r * 8 + f]);
}

__global__ void k_pool(const float* __restrict__ dinv, const float* __restrict__ acc2,
                       const float* __restrict__ b2, const int* __restrict__ batch,
                       float* __restrict__ pooled, float* __restrict__ cnt, int n) {
    int i = blockIdx.x * BLK + threadIdx.x;
    if (i >= n) return;
    float d = dinv[i];
    int g = batch[i];
#pragma unroll
    for (int f = 0; f < 8; f++) {
        float h = tanhf(d * acc2[i * 8 + f] + b2[f]);
        atomicAdd(&pooled[g * 8 + f], h);
    }
    atomicAdd(&cnt[g], 1.0f);
}

__global__ void k_out(const float* __restrict__ pooled, const float* __restrict__ cnt,
                      const float* __restrict__ W3, const float* __restrict__ b3,
                      float* __restrict__ out, int G) {
    int g = blockIdx.x * BLK + threadIdx.x;
    if (g >= G) return;
    float c = fmaxf(cnt[g], 1.0f);
    float s = 0.0f;
#pragma unroll
    for (int f = 0; f < 8; f++) s += pooled[g * 8 + f] * W3[f];
    out[g] = s / c + b3[0];
}

extern "C" void kernel_launch(void* const* d_in, const int* in_sizes, int n_in,
                              void* d_out, int out_size, void* d_ws, size_t ws_size,
                              hipStream_t stream) {
    const float* x    = (const float*)d_in[0];
    const int*   ei   = (const int*)d_in[1];
    const int*   batch= (const int*)d_in[2];
    const float* Wemb = (const float*)d_in[3];
    const float* bemb = (const float*)d_in[4];
    const float* W1   = (const float*)d_in[5];
    const float* b1   = (const float*)d_in[6];
    const float* W2   = (const float*)d_in[7];
    const float* b2   = (const float*)d_in[8];
    const float* W3   = (const float*)d_in[9];
    const float* b3   = (const float*)d_in[10];
    float* out = (float*)d_out;

    const int n = in_sizes[2];        // 100000
    const int E = in_sizes[1] / 2;    // 3200000
    const int G = out_size;           // 1024
    const int* row = ei;
    const int* col = ei + E;

    // workspace layout (floats): deg/dinv [n] | acc1 [16n] | u1region: u2[8n]+acc2[8n]=[16n] | pooled [8G] | cnt [G]
    float* ws     = (float*)d_ws;
    float* deg    = ws;               // n (becomes dinv)
    float* acc1   = deg + n;          // 16n
    float* u1     = acc1 + 16 * n;    // 16n (reused: u2 = first 8n, acc2 = second 8n after scatter1)
    float* u2     = u1;               // aliased after u1 is dead
    float* acc2   = u1 + 8 * n;
    float* pooled = u1 + 16 * n;      // 8G
    float* cnt    = pooled + 8 * G;   // G

    // But u1 must survive through scatter1 while u2/acc2 are written in k_node2
    // (after scatter1 completes) — aliasing is safe by stream ordering.

    int gridN = (n + BLK - 1) / BLK;
    int gridE = (E + BLK - 1) / BLK;

    k_init<<<gridN, BLK, 0, stream>>>(deg, pooled, cnt, n, G);
    k_deg<<<gridE, BLK, 0, stream>>>(col, deg, E);
    k_node1<<<gridN, BLK, 0, stream>>>(x, deg, Wemb, bemb, W1, u1, acc1, n);
    int tot1 = E * 16;
    k_scatter16<<<(tot1 + BLK - 1) / BLK, BLK, 0, stream>>>(row, col, u1, acc1, tot1);
    // NOTE: k_node2 reads acc1, writes u2/acc2 which alias u1 — u1 is dead now.
    // But k_node2 for node i writes u2[i*8..] which overlaps u1[i*16..] region of
    // node i/2 — since ALL reads of u1 happened in scatter16 (already complete),
    // this is safe.
    k_node2<<<gridN, BLK, 0, stream>>>(deg, acc1, b1, W2, u2, acc2, n);
    int tot2 = E * 8;
    k_scatter8<<<(tot2 + BLK - 1) / BLK, BLK, 0, stream>>>(row, col, u2, acc2, tot2);
    k_pool<<<gridN, BLK, 0, stream>>>(deg, acc2, b2, batch, pooled, cnt, n);
    k_out<<<(G + BLK - 1) / BLK, BLK, 0, stream>>>(pooled, cnt, W3, b3, out, G);
}

// Round 2
// 594.735 us; speedup vs baseline: 1.1802x; 1.1802x over previous
//
#include <hip/hip_runtime.h>

// GCN: N=100000 nodes (4 feats), E=3.2M edges, G=1024 graphs.
// out = mean-pool(tanh(gcn2(tanh(gcn1(embed(x)))))) @ W3.T + b3
//
// gcn_conv rewritten: u[i] = (h[i] @ W^T) * dinv[i];
// out[c] = dinv[c] * (sum_{edges r->c} u[r] + u[c]) + b   (self-loop folded in)
//
// R2: grid-stride k_deg (int4 loads, ~12 atomics in flight/thread);
//     block-per-graph pool+head fusion (batch sorted -> binary search, no atomics);
//     float4 node kernels; grid-stride scatters.

constexpr int BLK = 256;

__global__ void k_init(float* __restrict__ deg, int n) {
    int i = blockIdx.x * BLK + threadIdx.x;
    if (i < n) deg[i] = 1.0f;          // self-loop contribution to degree
}

__global__ void k_deg(const int4* __restrict__ col4, float* __restrict__ deg, int nq) {
    int stride = gridDim.x * BLK;
    for (int i = blockIdx.x * BLK + threadIdx.x; i < nq; i += stride) {
        int4 c = col4[i];
        atomicAdd(&deg[c.x], 1.0f);
        atomicAdd(&deg[c.y], 1.0f);
        atomicAdd(&deg[c.z], 1.0f);
        atomicAdd(&deg[c.w], 1.0f);
    }
}

// h0 = [x0*Wemb + bemb (4), x1, x2, x3]; u1 = (h0 @ W1^T) * dinv; acc1 seeded with u1
__global__ void k_node1(const float4* __restrict__ x, float* __restrict__ deg_dinv,
                        const float* __restrict__ Wemb, const float* __restrict__ bemb,
                        const float* __restrict__ W1,
                        float4* __restrict__ u1, float4* __restrict__ acc1, int n) {
    int i = blockIdx.x * BLK + threadIdx.x;
    if (i >= n) return;
    float4 xi = x[i];
    float h0[7];
#pragma unroll
    for (int j = 0; j < 4; j++) h0[j] = xi.x * Wemb[j] + bemb[j];
    h0[4] = xi.y; h0[5] = xi.z; h0[6] = xi.w;
    float d = rsqrtf(deg_dinv[i]);
    deg_dinv[i] = d;  // reuse buffer as dinv
    float s[16];
#pragma unroll
    for (int f = 0; f < 16; f++) {
        float t = 0.0f;
#pragma unroll
        for (int j = 0; j < 7; j++) t += h0[j] * W1[f * 7 + j];
        s[f] = t * d;
    }
#pragma unroll
    for (int q = 0; q < 4; q++) {
        float4 v = make_float4(s[q*4], s[q*4+1], s[q*4+2], s[q*4+3]);
        u1[i * 4 + q] = v;
        acc1[i * 4 + q] = v;   // self-loop seed
    }
}

__global__ void k_scatter16(const int* __restrict__ row, const int* __restrict__ col,
                            const float* __restrict__ u, float* __restrict__ acc, int total) {
    int stride = gridDim.x * BLK;
    for (int tid = blockIdx.x * BLK + threadIdx.x; tid < total; tid += stride) {
        int e = tid >> 4, f = tid & 15;
        atomicAdd(&acc[col[e] * 16 + f], u[row[e] * 16 + f]);
    }
}

__global__ void k_node2(const float* __restrict__ dinv, const float4* __restrict__ acc1,
                        const float* __restrict__ b1, const float* __restrict__ W2,
                        float4* __restrict__ u2, float4* __restrict__ acc2, int n) {
    int i = blockIdx.x * BLK + threadIdx.x;
    if (i >= n) return;
    float d = dinv[i];
    float h1[16];
#pragma unroll
    for (int q = 0; q < 4; q++) {
        float4 a = acc1[i * 4 + q];
        h1[q*4+0] = tanhf(d * a.x + b1[q*4+0]);
        h1[q*4+1] = tanhf(d * a.y + b1[q*4+1]);
        h1[q*4+2] = tanhf(d * a.z + b1[q*4+2]);
        h1[q*4+3] = tanhf(d * a.w + b1[q*4+3]);
    }
    float s[8];
#pragma unroll
    for (int g = 0; g < 8; g++) {
        float t = 0.0f;
#pragma unroll
        for (int f = 0; f < 16; f++) t += h1[f] * W2[g * 16 + f];
        s[g] = t * d;
    }
#pragma unroll
    for (int q = 0; q < 2; q++) {
        float4 v = make_float4(s[q*4], s[q*4+1], s[q*4+2], s[q*4+3]);
        u2[i * 2 + q] = v;
        acc2[i * 2 + q] = v;   // self-loop seed
    }
}

__global__ void k_scatter8(const int* __restrict__ row, const int* __restrict__ col,
                           const float* __restrict__ u, float* __restrict__ acc, int total) {
    int stride = gridDim.x * BLK;
    for (int tid = blockIdx.x * BLK + threadIdx.x; tid < total; tid += stride) {
        int e = tid >> 3, f = tid & 7;
        atomicAdd(&acc[col[e] * 8 + f], u[row[e] * 8 + f]);
    }
}

// One wave per graph. batch is SORTED -> binary search the node range, reduce
// tanh(dinv*acc2+b2) over it, mean, dot with W3. No atomics, fuses pool+head.
__global__ void k_pool_out(const float* __restrict__ dinv, const float4* __restrict__ acc2,
                           const float* __restrict__ b2, const int* __restrict__ batch,
                           const float* __restrict__ W3, const float* __restrict__ b3,
                           float* __restrict__ out, int n) {
    int g = blockIdx.x;
    int lane = threadIdx.x;           // 64 threads = 1 wave
    // lower_bound(batch, g) and lower_bound(batch, g+1), done redundantly per lane
    int lo = 0, hi = n;
    while (lo < hi) { int m = (lo + hi) >> 1; if (batch[m] < g) lo = m + 1; else hi = m; }
    int start = lo;
    hi = n;
    while (lo < hi) { int m = (lo + hi) >> 1; if (batch[m] < g + 1) lo = m + 1; else hi = m; }
    int end = lo;

    float s[8];
#pragma unroll
    for (int f = 0; f < 8; f++) s[f] = 0.0f;
    for (int i = start + lane; i < end; i += 64) {
        float d = dinv[i];
        float4 a0 = acc2[i * 2];
        float4 a1 = acc2[i * 2 + 1];
        s[0] += tanhf(d * a0.x + b2[0]);
        s[1] += tanhf(d * a0.y + b2[1]);
        s[2] += tanhf(d * a0.z + b2[2]);
        s[3] += tanhf(d * a0.w + b2[3]);
        s[4] += tanhf(d * a1.x + b2[4]);
        s[5] += tanhf(d * a1.y + b2[5]);
        s[6] += tanhf(d * a1.z + b2[6]);
        s[7] += tanhf(d * a1.w + b2[7]);
    }
#pragma unroll
    for (int off = 32; off >= 1; off >>= 1) {
#pragma unroll
        for (int f = 0; f < 8; f++) s[f] += __shfl_down(s[f], off, 64);
    }
    if (lane == 0) {
        float c = fmaxf((float)(end - start), 1.0f);
        float t = 0.0f;
#pragma unroll
        for (int f = 0; f < 8; f++) t += (s[f] / c) * W3[f];
        out[g] = t + b3[0];
    }
}

extern "C" void kernel_launch(void* const* d_in, const int* in_sizes, int n_in,
                              void* d_out, int out_size, void* d_ws, size_t ws_size,
                              hipStream_t stream) {
    const float* x    = (const float*)d_in[0];
    const int*   ei   = (const int*)d_in[1];
    const int*   batch= (const int*)d_in[2];
    const float* Wemb = (const float*)d_in[3];
    const float* bemb = (const float*)d_in[4];
    const float* W1   = (const float*)d_in[5];
    const float* b1   = (const float*)d_in[6];
    const float* W2   = (const float*)d_in[7];
    const float* b2   = (const float*)d_in[8];
    const float* W3   = (const float*)d_in[9];
    const float* b3   = (const float*)d_in[10];
    float* out = (float*)d_out;

    const int n = in_sizes[2];        // 100000
    const int E = in_sizes[1] / 2;    // 3200000
    const int G = out_size;           // 1024
    const int* row = ei;
    const int* col = ei + E;

    // workspace (floats): deg/dinv [n] | acc1 [16n] | u1 [16n]
    // (u2 = u1[0:8n], acc2 = u1[8n:16n] after u1 is dead — safe by stream order)
    float* ws     = (float*)d_ws;
    float* deg    = ws;               // n (becomes dinv)
    float* acc1   = deg + n;          // 16n
    float* u1     = acc1 + 16 * n;    // 16n
    float* u2     = u1;
    float* acc2   = u1 + 8 * n;

    int gridN = (n + BLK - 1) / BLK;

    k_init<<<gridN, BLK, 0, stream>>>(deg, n);
    k_deg<<<1024, BLK, 0, stream>>>((const int4*)col, deg, E / 4);
    k_node1<<<gridN, BLK, 0, stream>>>((const float4*)x, deg, Wemb, bemb, W1,
                                       (float4*)u1, (float4*)acc1, n);
    k_scatter16<<<32768, BLK, 0, stream>>>(row, col, u1, acc1, E * 16);
    k_node2<<<gridN, BLK, 0, stream>>>(deg, (const float4*)acc1, b1, W2,
                                       (float4*)u2, (float4*)acc2, n);
    k_scatter8<<<16384, BLK, 0, stream>>>(row, col, u2, acc2, E * 8);
    k_pool_out<<<G, 64, 0, stream>>>(deg, (const float4*)acc2, b2, batch, W3, b3, out, n);
}